// Round 2
// baseline (4986.749 us; speedup 1.0000x reference)
//
#include <hip/hip_runtime.h>

#define B   64
#define T   512
#define DIN 64
#define F   64
#define U   128
#define G3  384     // 3U
#define M2  256     // 2U
#define NH  4
#define KD  128
#define HD  512     // NH*KD

// ---------------- conv1d(same,k=3) + BN(inference) + ReLU ----------------
__global__ __launch_bounds__(256) void k_conv(const float* __restrict__ in,
        const float* __restrict__ cw, const float* __restrict__ cb,
        const float* __restrict__ gamma, const float* __restrict__ beta,
        const float* __restrict__ mean, const float* __restrict__ var,
        float* __restrict__ x1)
{
    __shared__ float w_s[3*64*64];   // 48 KB
    __shared__ float in_s[18*64];
    const int b  = blockIdx.y;
    const int t0 = blockIdx.x * 16;
    const int tid = threadIdx.x;
    for (int idx = tid; idx < 3*64*64; idx += 256) w_s[idx] = cw[idx];
    for (int idx = tid; idx < 18*64; idx += 256) {
        int row = idx >> 6;
        int d   = idx & 63;
        int t   = t0 - 1 + row;
        in_s[idx] = (t >= 0 && t < T) ? in[((size_t)b*T + t)*DIN + d] : 0.0f;
    }
    __syncthreads();
    const int f  = tid & 63;
    const int tl = tid >> 6;   // 0..3
    const float scale = gamma[f] * rsqrtf(var[f] + 1e-3f);
    const float shift = beta[f] - mean[f] * scale;
    const float bias  = cb[f];
    for (int q = 0; q < 4; ++q) {
        const int tt = tl*4 + q;   // 0..15
        float acc = bias;
        for (int tap = 0; tap < 3; ++tap) {
            const float* irow = &in_s[(tt + tap)*64];
            const float* wrow = &w_s[tap*64*64 + f];
            #pragma unroll 16
            for (int d = 0; d < 64; ++d) acc += irow[d] * wrow[d*64];
        }
        float v = acc * scale + shift;
        x1[((size_t)b*T + t0 + tt)*F + f] = fmaxf(v, 0.0f);
    }
}

// ------------- GEMM: C[R,N] (+)= A[R,K]@W[K,N] + bias -------------
// 32 rows per block; A tile staged in dynamic LDS (32*K floats, <=32 KB).
// W row stride = ldw, C row stride = ldc. accum!=0 -> C += A@W (no bias).
__global__ __launch_bounds__(384) void k_gemm(const float* __restrict__ A,
        const float* __restrict__ W, int ldw, const float* __restrict__ bias,
        float* __restrict__ C, int ldc, int K, int N, int accum)
{
    extern __shared__ float a_s[];
    const int r0   = blockIdx.x * 32;
    const int tid  = threadIdx.x;
    const int nthr = blockDim.x;
    for (int idx = tid; idx < 32*K; idx += nthr) a_s[idx] = A[(size_t)r0*K + idx];
    __syncthreads();
    for (int j = tid; j < N; j += nthr) {
        float acc[32];
        const float bj = (bias != nullptr && !accum) ? bias[j] : 0.0f;
        #pragma unroll
        for (int r = 0; r < 32; ++r) acc[r] = bj;
        for (int k4 = 0; k4 < K; k4 += 4) {
            const float w0 = W[(size_t)(k4+0)*ldw + j];
            const float w1 = W[(size_t)(k4+1)*ldw + j];
            const float w2 = W[(size_t)(k4+2)*ldw + j];
            const float w3 = W[(size_t)(k4+3)*ldw + j];
            #pragma unroll
            for (int r = 0; r < 32; ++r) {
                const float4 a4 = *reinterpret_cast<const float4*>(&a_s[r*K + k4]);
                acc[r] += a4.x*w0 + a4.y*w1 + a4.z*w2 + a4.w*w3;
            }
        }
        for (int r = 0; r < 32; ++r) {
            const size_t off = (size_t)(r0 + r)*ldc + j;
            if (accum) C[off] += acc[r];
            else       C[off]  = acc[r];
        }
    }
}

// ---------------- GRU scan: one block per (batch, direction) ----------------
__device__ __forceinline__ float sigmoidf_(float x){ return 1.0f/(1.0f + __expf(-x)); }
__device__ __forceinline__ float tanhf_(float x){ return 2.0f/(1.0f + __expf(-2.0f*x)) - 1.0f; }

__global__ __launch_bounds__(384, 2) void k_gru(const float* __restrict__ xg_f,
        const float* __restrict__ xg_b, const float* __restrict__ wh_f,
        const float* __restrict__ wh_b, const float* __restrict__ b_f,
        const float* __restrict__ b_b, float* __restrict__ yseq,
        float* __restrict__ hout)
{
    const int b   = blockIdx.x;
    const int dir = blockIdx.y;
    const float* xg = dir ? xg_b : xg_f;            // [B,T,3U]
    const float* wh = dir ? wh_b : wh_f;            // [U,3U]
    const float* bh_ptr = (dir ? b_b : b_f) + G3;   // b[1]
    const int j = threadIdx.x;                      // 0..383 = gate column

    float w[U];                                     // wh[:, j] in registers
    #pragma unroll
    for (int u = 0; u < U; ++u) w[u] = wh[(size_t)u*G3 + j];
    const float bh = bh_ptr[j];

    __shared__ __align__(16) float h_s[U];
    __shared__ float hg_s[G3];
    if (j < U) h_s[j] = 0.0f;
    __syncthreads();

    for (int step = 0; step < T; ++step) {
        const int t = dir ? (T - 1 - step) : step;
        const float4* h4 = reinterpret_cast<const float4*>(h_s);
        float a0 = bh, a1 = 0.f, a2 = 0.f, a3 = 0.f;
        #pragma unroll
        for (int u4 = 0; u4 < U/4; ++u4) {
            const float4 hv = h4[u4];
            a0 += hv.x*w[4*u4+0];
            a1 += hv.y*w[4*u4+1];
            a2 += hv.z*w[4*u4+2];
            a3 += hv.w*w[4*u4+3];
        }
        hg_s[j] = (a0 + a1) + (a2 + a3);
        __syncthreads();
        if (j < U) {
            const float* xrow = xg + ((size_t)b*T + t)*G3;
            const float z = sigmoidf_(xrow[j]     + hg_s[j]);
            const float r = sigmoidf_(xrow[U+j]   + hg_s[U+j]);
            const float n = tanhf_(xrow[2*U+j] + r*hg_s[2*U+j]);
            const float hnew = z*h_s[j] + (1.0f - z)*n;
            h_s[j] = hnew;
            if (yseq) yseq[((size_t)b*T + t)*M2 + dir*U + j] = hnew;
        }
        __syncthreads();
    }
    if (hout && j < U) hout[b*M2 + dir*U + j] = h_s[j];
}

// ---------------- flash attention (per head), one block per (q-tile, batch) ----------------
// Q/K/V/O are per-head [B,T,128] contiguous. O may alias Q (block reads its own
// q rows once at start, writes the same rows at the end).
// LDS: q tile 32x128 (16 KB) + K/V shared buffer 64x129 pad (33 KB) + p 8 KB = 57.6 KB.
__global__ __launch_bounds__(256) void k_attn(const float* __restrict__ Q,
        const float* __restrict__ Kp, const float* __restrict__ Vp,
        float* __restrict__ O)
{
    __shared__ float q_s[32*KD];      // 16 KB
    __shared__ float kv_s[64*129];    // 33 KB (pad 129 -> <=2-way banks everywhere)
    __shared__ float p_s[4*8*64];     // 8 KB  (wave, row, key)
    const int b   = blockIdx.y;
    const int qt  = blockIdx.x;       // 0..15, 32 q-rows each
    const size_t base = (size_t)b * T * KD;
    const int tid  = threadIdx.x;
    const int lane = tid & 63;
    const int wv   = tid >> 6;        // wave owns rows wv*8 .. wv*8+7 of the tile

    for (int idx = tid; idx < 32*KD; idx += 256)
        q_s[idx] = Q[base + (size_t)(qt*32)*KD + idx];

    float m[8], l[8], o0[8], o1[8];
    #pragma unroll
    for (int i = 0; i < 8; ++i) { m[i] = -1e30f; l[i] = 0.f; o0[i] = 0.f; o1[i] = 0.f; }

    for (int kg = 0; kg < 8; ++kg) {
        __syncthreads();              // kv_s free (prev PV done); covers q_s on iter 0
        for (int idx = tid; idx < 64*KD; idx += 256) {
            const int key = idx >> 7, d = idx & 127;
            kv_s[key*129 + d] = Kp[base + (size_t)(kg*64 + key)*KD + d];
        }
        __syncthreads();
        // scores: lane = key; K-tile read once per wave, reused across 8 rows
        float s[8];
        #pragma unroll
        for (int i = 0; i < 8; ++i) s[i] = 0.f;
        for (int d4 = 0; d4 < KD; d4 += 4) {
            const float k0 = kv_s[lane*129 + d4 + 0];
            const float k1 = kv_s[lane*129 + d4 + 1];
            const float k2 = kv_s[lane*129 + d4 + 2];
            const float k3 = kv_s[lane*129 + d4 + 3];
            #pragma unroll
            for (int i = 0; i < 8; ++i) {
                const float4 q4 = *reinterpret_cast<const float4*>(&q_s[(wv*8+i)*KD + d4]);
                s[i] += q4.x*k0 + q4.y*k1 + q4.z*k2 + q4.w*k3;
            }
        }
        #pragma unroll
        for (int i = 0; i < 8; ++i) {
            const float sc = s[i] * 0.08838834764831845f;   // 1/sqrt(128)
            float mx = sc;
            #pragma unroll
            for (int off = 32; off; off >>= 1) mx = fmaxf(mx, __shfl_xor(mx, off));
            const float mnew  = fmaxf(m[i], mx);
            const float p     = __expf(sc - mnew);
            const float alpha = __expf(m[i] - mnew);
            float ps = p;
            #pragma unroll
            for (int off = 32; off; off >>= 1) ps += __shfl_xor(ps, off);
            l[i]  = l[i]*alpha + ps;
            o0[i] *= alpha;  o1[i] *= alpha;
            m[i]  = mnew;
            p_s[wv*512 + i*64 + lane] = p;
        }
        __syncthreads();              // all waves done reading K from kv_s
        for (int idx = tid; idx < 64*KD; idx += 256) {
            const int key = idx >> 7, d = idx & 127;
            kv_s[key*129 + d] = Vp[base + (size_t)(kg*64 + key)*KD + d];
        }
        __syncthreads();
        // PV: lane = output dim slot (d=lane, d=64+lane); V read once per wave
        for (int k = 0; k < 64; ++k) {
            const float v0 = kv_s[k*129 + lane];
            const float v1 = kv_s[k*129 + 64 + lane];
            #pragma unroll
            for (int i = 0; i < 8; ++i) {
                const float pk = p_s[wv*512 + i*64 + k];   // uniform broadcast
                o0[i] += pk*v0;
                o1[i] += pk*v1;
            }
        }
    }
    #pragma unroll
    for (int i = 0; i < 8; ++i) {
        const int row = qt*32 + wv*8 + i;
        const float inv = 1.0f / l[i];
        O[base + (size_t)row*KD + lane]      = o0[i]*inv;
        O[base + (size_t)row*KD + 64 + lane] = o1[i]*inv;
    }
}

// ---------------- residual bias add (in-place) ----------------
__global__ __launch_bounds__(256) void k_addbias(float* __restrict__ x,
        const float* __restrict__ bo)
{
    const int i = blockIdx.x*256 + threadIdx.x;
    x[i] += bo[i & (M2-1)];
}

// ---------------- dense head ----------------
__global__ void k_dense(const float* __restrict__ h2, const float* __restrict__ dw,
                        const float* __restrict__ db, float* __restrict__ out)
{
    const int b = threadIdx.x;
    float acc = db[0];
    for (int mm = 0; mm < M2; ++mm) acc += h2[b*M2 + mm] * dw[mm];
    out[b] = acc;
}

extern "C" void kernel_launch(void* const* d_in, const int* in_sizes, int n_in,
                              void* d_out, int out_size, void* d_ws, size_t ws_size,
                              hipStream_t stream)
{
    const float* inputs  = (const float*)d_in[0];
    const float* conv_w  = (const float*)d_in[1];
    const float* conv_b  = (const float*)d_in[2];
    const float* bn_g    = (const float*)d_in[3];
    const float* bn_b    = (const float*)d_in[4];
    const float* bn_m    = (const float*)d_in[5];
    const float* bn_v    = (const float*)d_in[6];
    const float* g1f_wx  = (const float*)d_in[7];
    const float* g1f_wh  = (const float*)d_in[8];
    const float* g1f_b   = (const float*)d_in[9];
    const float* g1b_wx  = (const float*)d_in[10];
    const float* g1b_wh  = (const float*)d_in[11];
    const float* g1b_b   = (const float*)d_in[12];
    const float* wq      = (const float*)d_in[13];
    const float* bq      = (const float*)d_in[14];
    const float* wk      = (const float*)d_in[15];
    const float* bk      = (const float*)d_in[16];
    const float* wv_     = (const float*)d_in[17];
    const float* bv      = (const float*)d_in[18];
    const float* wo      = (const float*)d_in[19];
    const float* bo      = (const float*)d_in[20];
    const float* g2f_wx  = (const float*)d_in[21];
    const float* g2f_wh  = (const float*)d_in[22];
    const float* g2f_b   = (const float*)d_in[23];
    const float* g2b_wx  = (const float*)d_in[24];
    const float* g2b_wh  = (const float*)d_in[25];
    const float* g2b_b   = (const float*)d_in[26];
    const float* dense_w = (const float*)d_in[27];
    const float* dense_b = (const float*)d_in[28];
    float* out = (float*)d_out;
    (void)in_sizes; (void)n_in; (void)out_size; (void)ws_size;

    // ---- workspace plan (floats): total exactly 128 MiB ----
    // stage 1-3:  x1@0 (2M) | xg1f@8388608 (12.58M) | xg1b@20971520 (12.58M)
    //             y1@0 (8.39M) overwrites dead x1
    // attn:       O_h@8388608+h*4194304 (x4) | kh@25165824 | vh@29360128  (end 33554432)
    // resid:      x2 == y1 (in-place init + per-head accumulate)
    // gru2:       xg2f@8388608 | xg2b@20971520 (overwrite dead O/k/v) | h2@0 (x2 dead)
    float* ws   = (float*)d_ws;
    float* x1   = ws;
    float* y1   = ws;
    float* xg1f = ws +  8388608;
    float* xg1b = ws + 20971520;
    float* Oh0  = ws +  8388608;
    float* Oh1  = ws + 12582912;
    float* Oh2  = ws + 16777216;
    float* Oh3  = ws + 20971520;
    float* Ohs[4] = { Oh0, Oh1, Oh2, Oh3 };
    float* kh   = ws + 25165824;
    float* vh   = ws + 29360128;
    float* x2   = ws;                 // == y1
    float* xg2f = ws +  8388608;
    float* xg2b = ws + 20971520;
    float* h2   = ws;                 // after x2 dead

    const int RB = B*T/32;            // 1024 row-blocks

    // 1. conv + BN + ReLU -> x1
    k_conv<<<dim3(T/16, B), 256, 0, stream>>>(inputs, conv_w, conv_b,
                                              bn_g, bn_b, bn_m, bn_v, x1);
    // 2. GRU1 input gates
    k_gemm<<<RB, 384, 32*64*4, stream>>>(x1, g1f_wx, G3, g1f_b, xg1f, G3, 64, G3, 0);
    k_gemm<<<RB, 384, 32*64*4, stream>>>(x1, g1b_wx, G3, g1b_b, xg1b, G3, 64, G3, 0);
    // 3. GRU1 scan -> y1
    k_gru<<<dim3(B,2), 384, 0, stream>>>(xg1f, xg1b, g1f_wh, g1b_wh, g1f_b, g1b_b, y1, nullptr);
    // 4. per-head QKV + attention (O in-place over Q)
    for (int h = 0; h < NH; ++h) {
        k_gemm<<<RB, 128, 32*256*4, stream>>>(y1, wq  + h*KD, HD, bq + h*KD, Ohs[h], KD, M2, KD, 0);
        k_gemm<<<RB, 128, 32*256*4, stream>>>(y1, wk  + h*KD, HD, bk + h*KD, kh,     KD, M2, KD, 0);
        k_gemm<<<RB, 128, 32*256*4, stream>>>(y1, wv_ + h*KD, HD, bv + h*KD, vh,     KD, M2, KD, 0);
        k_attn<<<dim3(T/32, B), 256, 0, stream>>>(Ohs[h], kh, vh, Ohs[h]);
    }
    // 5. residual: x2 = y1 + bo (in-place), then += O_h @ wo[h]
    k_addbias<<<B*T*M2/256, 256, 0, stream>>>(x2, bo);
    for (int h = 0; h < NH; ++h)
        k_gemm<<<RB, 256, 32*128*4, stream>>>(Ohs[h], wo + h*KD*M2, M2, nullptr, x2, M2, KD, M2, 1);
    // 6. GRU2 input gates
    k_gemm<<<RB, 384, 32*256*4, stream>>>(x2, g2f_wx, G3, g2f_b, xg2f, G3, M2, G3, 0);
    k_gemm<<<RB, 384, 32*256*4, stream>>>(x2, g2b_wx, G3, g2b_b, xg2b, G3, M2, G3, 0);
    // 7. GRU2 scan -> h2 (final states only)
    k_gru<<<dim3(B,2), 384, 0, stream>>>(xg2f, xg2b, g2f_wh, g2b_wh, g2f_b, g2b_b, nullptr, h2);
    // 8. dense head
    k_dense<<<1, 64, 0, stream>>>(h2, dense_w, dense_b, out);
}

// Round 3
// 2725.342 us; speedup vs baseline: 1.8298x; 1.8298x over previous
//
#include <hip/hip_runtime.h>
#include <hip/hip_bf16.h>

#define B   64
#define T   512
#define DIN 64
#define F   64
#define U   128
#define G3  384     // 3U
#define M2  256     // 2U
#define NH  4
#define KD  128
#define HD  512     // NH*KD

typedef __attribute__((ext_vector_type(8))) short short8;
typedef __attribute__((ext_vector_type(4))) float floatx4;
typedef __hip_bfloat16 bf16;

// ---------------- weight transpose + cast: dst[n][k] = (bf16)src[k][n] ----------------
__global__ __launch_bounds__(256) void k_wcast(const float* __restrict__ src,
        bf16* __restrict__ dst, int K, int N)
{
    const int i = blockIdx.x*256 + threadIdx.x;
    if (i < K*N) {
        const int k = i / N, n = i - k*N;
        dst[n*K + k] = __float2bfloat16(src[i]);
    }
}

// ---------------- conv1d(same,k=3) + BN(inference) + ReLU -> bf16 ----------------
__global__ __launch_bounds__(256) void k_conv(const float* __restrict__ in,
        const float* __restrict__ cw, const float* __restrict__ cb,
        const float* __restrict__ gamma, const float* __restrict__ beta,
        const float* __restrict__ mean, const float* __restrict__ var,
        bf16* __restrict__ x1h)
{
    __shared__ float w_s[3*64*64];   // 48 KB
    __shared__ float in_s[18*64];
    const int b  = blockIdx.y;
    const int t0 = blockIdx.x * 16;
    const int tid = threadIdx.x;
    for (int idx = tid; idx < 3*64*64; idx += 256) w_s[idx] = cw[idx];
    for (int idx = tid; idx < 18*64; idx += 256) {
        int row = idx >> 6;
        int d   = idx & 63;
        int t   = t0 - 1 + row;
        in_s[idx] = (t >= 0 && t < T) ? in[((size_t)b*T + t)*DIN + d] : 0.0f;
    }
    __syncthreads();
    const int f  = tid & 63;
    const int tl = tid >> 6;   // 0..3
    const float scale = gamma[f] * rsqrtf(var[f] + 1e-3f);
    const float shift = beta[f] - mean[f] * scale;
    const float bias  = cb[f];
    for (int q = 0; q < 4; ++q) {
        const int tt = tl*4 + q;   // 0..15
        float acc = bias;
        for (int tap = 0; tap < 3; ++tap) {
            const float* irow = &in_s[(tt + tap)*64];
            const float* wrow = &w_s[tap*64*64 + f];
            #pragma unroll 16
            for (int d = 0; d < 64; ++d) acc += irow[d] * wrow[d*64];
        }
        float v = acc * scale + shift;
        x1h[((size_t)b*T + t0 + tt)*F + f] = __float2bfloat16(fmaxf(v, 0.0f));
    }
}

// ------------- MFMA bf16 GEMM: C[R,N] = A[R,K] @ Bt[N,K]^T + bias (+resid) -------------
// 128x128 tile per block, BK=32, 256 threads = 4 waves (2x2), 4x4 16x16 frags/wave.
// A row-major bf16 [R,K]; Bt row-major bf16 [N,K] (pre-transposed weights).
// outF (fp32) and/or outH (bf16), optional bf16 residual added.
__global__ __launch_bounds__(256) void k_gemm(const bf16* __restrict__ A,
        const bf16* __restrict__ Bt, const float* __restrict__ bias,
        const bf16* __restrict__ resid, float* __restrict__ outF,
        bf16* __restrict__ outH, int K, int N)
{
    __shared__ short As[128*32];   // 8 KB
    __shared__ short Bs[128*32];   // 8 KB
    const int nbase = blockIdx.x * 128;
    const int rbase = blockIdx.y * 128;
    const int tid  = threadIdx.x;
    const int lane = tid & 63;
    const int wv   = tid >> 6;
    const int wm   = wv & 1;        // row half
    const int wn   = wv >> 1;       // col half
    const int l16  = lane & 15;
    const int quad = lane >> 4;

    floatx4 acc[4][4];
    #pragma unroll
    for (int i = 0; i < 4; ++i)
        #pragma unroll
        for (int j = 0; j < 4; ++j) acc[i][j] = (floatx4)0.0f;

    const int row  = tid >> 1;           // staging: 2 threads per tile-row
    const int koff = (tid & 1) * 16;     // 16 bf16 = 32 B per thread
    const int nK = K >> 5;
    for (int kt = 0; kt < nK; ++kt) {
        if (kt) __syncthreads();
        {
            const float4* ga = reinterpret_cast<const float4*>(
                &A[(size_t)(rbase + row)*K + kt*32 + koff]);
            const float4 a0 = ga[0], a1 = ga[1];
            const float4* gb = reinterpret_cast<const float4*>(
                &Bt[(size_t)(nbase + row)*K + kt*32 + koff]);
            const float4 b0 = gb[0], b1 = gb[1];
            float4* la = reinterpret_cast<float4*>(&As[row*32 + koff]);
            la[0] = a0; la[1] = a1;
            float4* lb = reinterpret_cast<float4*>(&Bs[row*32 + koff]);
            lb[0] = b0; lb[1] = b1;
        }
        __syncthreads();
        short8 af[4], bf[4];
        #pragma unroll
        for (int i = 0; i < 4; ++i)
            af[i] = *reinterpret_cast<const short8*>(&As[(wm*64 + i*16 + l16)*32 + quad*8]);
        #pragma unroll
        for (int j = 0; j < 4; ++j)
            bf[j] = *reinterpret_cast<const short8*>(&Bs[(wn*64 + j*16 + l16)*32 + quad*8]);
        #pragma unroll
        for (int i = 0; i < 4; ++i)
            #pragma unroll
            for (int j = 0; j < 4; ++j)
                acc[i][j] = __builtin_amdgcn_mfma_f32_16x16x32_bf16(af[i], bf[j], acc[i][j], 0, 0, 0);
    }

    // epilogue: C[row,col], row = rbase+wm*64+i*16+quad*4+r, col = nbase+wn*64+j*16+l16
    #pragma unroll
    for (int j = 0; j < 4; ++j) {
        const int gcol = nbase + wn*64 + j*16 + l16;
        const float bj = bias[gcol];
        #pragma unroll
        for (int i = 0; i < 4; ++i) {
            #pragma unroll
            for (int r = 0; r < 4; ++r) {
                const int grow = rbase + wm*64 + i*16 + quad*4 + r;
                const size_t off = (size_t)grow*N + gcol;
                float v = acc[i][j][r] + bj;
                if (resid) v += __bfloat162float(resid[off]);
                if (outF) outF[off] = v;
                if (outH) outH[off] = __float2bfloat16(v);
            }
        }
    }
}

// ---------------- GRU scan: one block per (batch, direction) ----------------
__device__ __forceinline__ float sigmoidf_(float x){ return 1.0f/(1.0f + __expf(-x)); }
__device__ __forceinline__ float tanhf_(float x){ return 2.0f/(1.0f + __expf(-2.0f*x)) - 1.0f; }

__device__ __forceinline__ float xload(const float* p){ return *p; }
__device__ __forceinline__ float xload(const bf16* p){ return __bfloat162float(*p); }

template<typename XT>
__global__ __launch_bounds__(384, 1) void k_gru(const XT* __restrict__ xg_f,
        const XT* __restrict__ xg_b, const float* __restrict__ wh_f,
        const float* __restrict__ wh_b, const float* __restrict__ b_f,
        const float* __restrict__ b_b, bf16* __restrict__ yseq,
        float* __restrict__ hout)
{
    const int b   = blockIdx.x;
    const int dir = blockIdx.y;
    const XT* xg = dir ? xg_b : xg_f;               // [B,T,3U]
    const float* wh = dir ? wh_b : wh_f;            // [U,3U]
    const float* bh_ptr = (dir ? b_b : b_f) + G3;   // b[1]
    const int j = threadIdx.x;                      // gate column 0..383

    // wh[:, j] register-resident as 64 float2 (u-pairs). launch_bounds(384,1)
    // allows ~150 VGPRs so this does NOT spill (round-1: VGPR=120 -> spilled).
    float2 w2[64];
    #pragma unroll
    for (int u = 0; u < 64; ++u) {
        w2[u].x = wh[(size_t)(2*u  )*G3 + j];
        w2[u].y = wh[(size_t)(2*u+1)*G3 + j];
    }
    const float bh = bh_ptr[j];

    __shared__ __align__(16) float h_s[U];
    __shared__ float hg_s[G3];
    if (j < U) h_s[j] = 0.0f;
    __syncthreads();

    for (int step = 0; step < T; ++step) {
        const int t = dir ? (T - 1 - step) : step;
        // prefetch this step's input gates (independent of h -> overlaps matvec)
        float xz = 0.f, xr = 0.f, xn = 0.f;
        if (j < U) {
            const XT* xrow = xg + ((size_t)b*T + t)*G3;
            xz = xload(xrow + j);
            xr = xload(xrow + U + j);
            xn = xload(xrow + 2*U + j);
        }
        // matvec: h (LDS, same-address broadcast reads = conflict-free) x w (regs)
        const float4* h4 = reinterpret_cast<const float4*>(h_s);
        float a0 = 0.f, a1 = 0.f, a2 = 0.f, a3 = 0.f;
        #pragma unroll
        for (int u = 0; u < 32; ++u) {
            const float4 hv = h4[u];
            a0 = fmaf(hv.x, w2[2*u].x,   a0);
            a1 = fmaf(hv.y, w2[2*u].y,   a1);
            a2 = fmaf(hv.z, w2[2*u+1].x, a2);
            a3 = fmaf(hv.w, w2[2*u+1].y, a3);
        }
        hg_s[j] = ((a0 + a1) + (a2 + a3)) + bh;
        __syncthreads();
        if (j < U) {
            const float z = sigmoidf_(xz + hg_s[j]);
            const float r = sigmoidf_(xr + hg_s[U+j]);
            const float n = tanhf_(xn + r*hg_s[2*U+j]);
            const float hnew = z*h_s[j] + (1.0f - z)*n;
            h_s[j] = hnew;
            if (yseq) yseq[((size_t)b*T + t)*M2 + dir*U + j] = __float2bfloat16(hnew);
        }
        __syncthreads();
    }
    if (hout && j < U) hout[b*M2 + dir*U + j] = h_s[j];
}

// ---------------- flash attention, one block per (q-tile, batch, head) ----------------
// Q/K/V/O: [B,T,HD] bf16, head h at column offset h*KD. O aliases Q (block reads its
// own 32 q rows once at start, writes the same rows at the end; rows x head-cols are
// touched by exactly one block).
__global__ __launch_bounds__(256) void k_attn(const bf16* __restrict__ Q,
        const bf16* __restrict__ Kp, const bf16* __restrict__ Vp,
        bf16* __restrict__ O)
{
    __shared__ float q_s[32*KD];      // 16 KB
    __shared__ float kv_s[64*129];    // 33 KB (pad 129)
    __shared__ float p_s[4*8*64];     // 8 KB  (wave, row, key)
    const int qt = blockIdx.x;        // 0..15
    const int b  = blockIdx.y;
    const int h  = blockIdx.z;
    const size_t base = (size_t)b * T * HD + (size_t)h * KD;
    const int tid  = threadIdx.x;
    const int lane = tid & 63;
    const int wv   = tid >> 6;        // wave owns rows wv*8 .. wv*8+7

    for (int idx = tid; idx < 32*KD; idx += 256) {
        const int r = idx >> 7, d = idx & 127;
        q_s[idx] = __bfloat162float(Q[base + (size_t)(qt*32 + r)*HD + d]);
    }

    float m[8], l[8], o0[8], o1[8];
    #pragma unroll
    for (int i = 0; i < 8; ++i) { m[i] = -1e30f; l[i] = 0.f; o0[i] = 0.f; o1[i] = 0.f; }

    for (int kg = 0; kg < 8; ++kg) {
        __syncthreads();              // kv_s free; covers q_s on iter 0
        for (int idx = tid; idx < 64*KD; idx += 256) {
            const int key = idx >> 7, d = idx & 127;
            kv_s[key*129 + d] = __bfloat162float(Kp[base + (size_t)(kg*64 + key)*HD + d]);
        }
        __syncthreads();
        float s[8];
        #pragma unroll
        for (int i = 0; i < 8; ++i) s[i] = 0.f;
        for (int d4 = 0; d4 < KD; d4 += 4) {
            const float k0 = kv_s[lane*129 + d4 + 0];
            const float k1 = kv_s[lane*129 + d4 + 1];
            const float k2 = kv_s[lane*129 + d4 + 2];
            const float k3 = kv_s[lane*129 + d4 + 3];
            #pragma unroll
            for (int i = 0; i < 8; ++i) {
                const float4 q4 = *reinterpret_cast<const float4*>(&q_s[(wv*8+i)*KD + d4]);
                s[i] += q4.x*k0 + q4.y*k1 + q4.z*k2 + q4.w*k3;
            }
        }
        #pragma unroll
        for (int i = 0; i < 8; ++i) {
            const float sc = s[i] * 0.08838834764831845f;   // 1/sqrt(128)
            float mx = sc;
            #pragma unroll
            for (int off = 32; off; off >>= 1) mx = fmaxf(mx, __shfl_xor(mx, off));
            const float mnew  = fmaxf(m[i], mx);
            const float p     = __expf(sc - mnew);
            const float alpha = __expf(m[i] - mnew);
            float ps = p;
            #pragma unroll
            for (int off = 32; off; off >>= 1) ps += __shfl_xor(ps, off);
            l[i]  = l[i]*alpha + ps;
            o0[i] *= alpha;  o1[i] *= alpha;
            m[i]  = mnew;
            p_s[wv*512 + i*64 + lane] = p;
        }
        __syncthreads();
        for (int idx = tid; idx < 64*KD; idx += 256) {
            const int key = idx >> 7, d = idx & 127;
            kv_s[key*129 + d] = __bfloat162float(Vp[base + (size_t)(kg*64 + key)*HD + d]);
        }
        __syncthreads();
        for (int k = 0; k < 64; ++k) {
            const float v0 = kv_s[k*129 + lane];
            const float v1 = kv_s[k*129 + 64 + lane];
            #pragma unroll
            for (int i = 0; i < 8; ++i) {
                const float pk = p_s[wv*512 + i*64 + k];
                o0[i] += pk*v0;
                o1[i] += pk*v1;
            }
        }
    }
    #pragma unroll
    for (int i = 0; i < 8; ++i) {
        const int row = qt*32 + wv*8 + i;
        const float inv = 1.0f / l[i];
        O[base + (size_t)row*HD + lane]      = __float2bfloat16(o0[i]*inv);
        O[base + (size_t)row*HD + 64 + lane] = __float2bfloat16(o1[i]*inv);
    }
}

// ---------------- dense head ----------------
__global__ void k_dense(const float* __restrict__ h2, const float* __restrict__ dw,
                        const float* __restrict__ db, float* __restrict__ out)
{
    const int b = threadIdx.x;
    float acc = db[0];
    for (int mm = 0; mm < M2; ++mm) acc += h2[b*M2 + mm] * dw[mm];
    out[b] = acc;
}

extern "C" void kernel_launch(void* const* d_in, const int* in_sizes, int n_in,
                              void* d_out, int out_size, void* d_ws, size_t ws_size,
                              hipStream_t stream)
{
    const float* inputs  = (const float*)d_in[0];
    const float* conv_w  = (const float*)d_in[1];
    const float* conv_b  = (const float*)d_in[2];
    const float* bn_g    = (const float*)d_in[3];
    const float* bn_b    = (const float*)d_in[4];
    const float* bn_m    = (const float*)d_in[5];
    const float* bn_v    = (const float*)d_in[6];
    const float* g1f_wx  = (const float*)d_in[7];
    const float* g1f_wh  = (const float*)d_in[8];
    const float* g1f_b   = (const float*)d_in[9];
    const float* g1b_wx  = (const float*)d_in[10];
    const float* g1b_wh  = (const float*)d_in[11];
    const float* g1b_b   = (const float*)d_in[12];
    const float* wq      = (const float*)d_in[13];
    const float* bq      = (const float*)d_in[14];
    const float* wk      = (const float*)d_in[15];
    const float* bk      = (const float*)d_in[16];
    const float* wv_     = (const float*)d_in[17];
    const float* bv      = (const float*)d_in[18];
    const float* wo      = (const float*)d_in[19];
    const float* bo      = (const float*)d_in[20];
    const float* g2f_wx  = (const float*)d_in[21];
    const float* g2f_wh  = (const float*)d_in[22];
    const float* g2f_b   = (const float*)d_in[23];
    const float* g2b_wx  = (const float*)d_in[24];
    const float* g2b_wh  = (const float*)d_in[25];
    const float* g2b_b   = (const float*)d_in[26];
    const float* dense_w = (const float*)d_in[27];
    const float* dense_b = (const float*)d_in[28];
    float* out = (float*)d_out;
    (void)in_sizes; (void)n_in; (void)out_size; (void)ws_size;

    // ---- workspace plan (float-slot offsets into 128 MiB = 33,554,432 fslots) ----
    // [0, 393216):           bf16 transposed weights (permanent)
    // phase A: x1h@393216(1.05M) xg1f@1441792(f32,12.58M) xg1b@14024704(f32,12.58M)
    //          y1h@26607616(bf16,4.19M fslots)                   peak 30.80M ok
    // phase B: qh@393216 kh@8781824 vh@17170432 (bf16 [B,T,512] = 8.39M fslots each)
    //          Oh = qh (in-place); y1h live                       peak 30.80M ok
    // phase C: x2h@17170432 (bf16, 4.19M fslots, over dead vh)
    // phase D: xg2f@393216 xg2b@6684672 (bf16, 6.29M fslots each, over dead Oh)
    //          h2@12976128 (fp32, 16K)
    float* ws = (float*)d_ws;
    bf16* wb = (bf16*)ws;
    bf16* g1fT = wb;            // [384,64]
    bf16* g1bT = wb + 24576;    // [384,64]
    bf16* wqT  = wb + 49152;    // [512,256]
    bf16* wkT  = wb + 180224;
    bf16* wvT  = wb + 311296;
    bf16* woT  = wb + 442368;   // [256,512]
    bf16* g2fT = wb + 573440;   // [384,256]
    bf16* g2bT = wb + 671744;   // ends 770048 elems < 786432

    bf16*  x1h  = (bf16*)(ws + 393216);     // [B,T,64]
    float* xg1f = ws + 1441792;             // [B,T,384] fp32
    float* xg1b = ws + 14024704;            // [B,T,384] fp32
    bf16*  y1h  = (bf16*)(ws + 26607616);   // [B,T,256]
    bf16*  qh   = (bf16*)(ws + 393216);     // [B,T,512]
    bf16*  kh   = (bf16*)(ws + 8781824);
    bf16*  vh   = (bf16*)(ws + 17170432);
    bf16*  Oh   = qh;                       // in-place
    bf16*  x2h  = (bf16*)(ws + 17170432);   // [B,T,256] (over dead vh)
    bf16*  xg2f = (bf16*)(ws + 393216);     // [B,T,384]
    bf16*  xg2b = (bf16*)(ws + 6684672);
    float* h2   = ws + 12976128;            // [B,256]

    // 0. weight casts (tiny)
    k_wcast<<<(64*384+255)/256, 256, 0, stream>>>(g1f_wx, g1fT, 64, 384);
    k_wcast<<<(64*384+255)/256, 256, 0, stream>>>(g1b_wx, g1bT, 64, 384);
    k_wcast<<<(256*512+255)/256, 256, 0, stream>>>(wq,  wqT, 256, 512);
    k_wcast<<<(256*512+255)/256, 256, 0, stream>>>(wk,  wkT, 256, 512);
    k_wcast<<<(256*512+255)/256, 256, 0, stream>>>(wv_, wvT, 256, 512);
    k_wcast<<<(512*256+255)/256, 256, 0, stream>>>(wo,  woT, 512, 256);
    k_wcast<<<(256*384+255)/256, 256, 0, stream>>>(g2f_wx, g2fT, 256, 384);
    k_wcast<<<(256*384+255)/256, 256, 0, stream>>>(g2b_wx, g2bT, 256, 384);

    // 1. conv + BN + ReLU -> x1h (bf16)
    k_conv<<<dim3(T/16, B), 256, 0, stream>>>(inputs, conv_w, conv_b,
                                              bn_g, bn_b, bn_m, bn_v, x1h);
    // 2. GRU1 input gates (fp32 out)
    k_gemm<<<dim3(3, 256), 256, 0, stream>>>(x1h, g1fT, g1f_b, nullptr, xg1f, nullptr, 64, G3);
    k_gemm<<<dim3(3, 256), 256, 0, stream>>>(x1h, g1bT, g1b_b, nullptr, xg1b, nullptr, 64, G3);
    // 3. GRU1 scan -> y1h (bf16)
    k_gru<float><<<dim3(B,2), 384, 0, stream>>>(xg1f, xg1b, g1f_wh, g1b_wh,
                                                g1f_b, g1b_b, y1h, nullptr);
    // 4. QKV projections (bf16 out)
    k_gemm<<<dim3(4, 256), 256, 0, stream>>>(y1h, wqT, bq, nullptr, nullptr, qh, 256, HD);
    k_gemm<<<dim3(4, 256), 256, 0, stream>>>(y1h, wkT, bk, nullptr, nullptr, kh, 256, HD);
    k_gemm<<<dim3(4, 256), 256, 0, stream>>>(y1h, wvT, bv, nullptr, nullptr, vh, 256, HD);
    // 5. attention, O in-place over Q
    k_attn<<<dim3(T/32, B, NH), 256, 0, stream>>>(qh, kh, vh, Oh);
    // 6. output projection + bias + residual(y1h) -> x2h (bf16)
    k_gemm<<<dim3(2, 256), 256, 0, stream>>>(Oh, woT, bo, y1h, nullptr, x2h, HD, M2);
    // 7. GRU2 input gates (bf16 out)
    k_gemm<<<dim3(3, 256), 256, 0, stream>>>(x2h, g2fT, g2f_b, nullptr, nullptr, xg2f, 256, G3);
    k_gemm<<<dim3(3, 256), 256, 0, stream>>>(x2h, g2bT, g2b_b, nullptr, nullptr, xg2b, 256, G3);
    // 8. GRU2 scan -> h2 (final states)
    k_gru<bf16><<<dim3(B,2), 384, 0, stream>>>(xg2f, xg2b, g2f_wh, g2b_wh,
                                               g2f_b, g2b_b, nullptr, h2);
    // 9. dense head
    k_dense<<<1, 64, 0, stream>>>(h2, dense_w, dense_b, out);
}

// Round 4
// 1873.151 us; speedup vs baseline: 2.6622x; 1.4550x over previous
//
#include <hip/hip_runtime.h>
#include <hip/hip_bf16.h>

#define B   64
#define T   512
#define DIN 64
#define F   64
#define U   128
#define G3  384     // 3U
#define M2  256     // 2U
#define NH  4
#define KD  128
#define HD  512     // NH*KD
#define BT  (B*T)   // 32768

typedef __attribute__((ext_vector_type(8))) short short8;
typedef __attribute__((ext_vector_type(4))) float floatx4;
typedef __hip_bfloat16 bf16;

// ---------------- weight transpose + cast: dst[n][k] = (bf16)src[k][n] ----------------
__global__ __launch_bounds__(256) void k_wcast(const float* __restrict__ src,
        bf16* __restrict__ dst, int K, int N)
{
    const int i = blockIdx.x*256 + threadIdx.x;
    if (i < K*N) {
        const int k = i / N, n = i - k*N;
        dst[n*K + k] = __float2bfloat16(src[i]);
    }
}

// ---------------- conv1d(same,k=3) + BN(inference) + ReLU -> bf16 ----------------
__global__ __launch_bounds__(256) void k_conv(const float* __restrict__ in,
        const float* __restrict__ cw, const float* __restrict__ cb,
        const float* __restrict__ gamma, const float* __restrict__ beta,
        const float* __restrict__ mean, const float* __restrict__ var,
        bf16* __restrict__ x1h)
{
    __shared__ float w_s[3*64*64];   // 48 KB
    __shared__ float in_s[18*64];
    const int b  = blockIdx.y;
    const int t0 = blockIdx.x * 16;
    const int tid = threadIdx.x;
    for (int idx = tid; idx < 3*64*64; idx += 256) w_s[idx] = cw[idx];
    for (int idx = tid; idx < 18*64; idx += 256) {
        int row = idx >> 6;
        int d   = idx & 63;
        int t   = t0 - 1 + row;
        in_s[idx] = (t >= 0 && t < T) ? in[((size_t)b*T + t)*DIN + d] : 0.0f;
    }
    __syncthreads();
    const int f  = tid & 63;
    const int tl = tid >> 6;   // 0..3
    const float scale = gamma[f] * rsqrtf(var[f] + 1e-3f);
    const float shift = beta[f] - mean[f] * scale;
    const float bias  = cb[f];
    for (int q = 0; q < 4; ++q) {
        const int tt = tl*4 + q;   // 0..15
        float acc = bias;
        for (int tap = 0; tap < 3; ++tap) {
            const float* irow = &in_s[(tt + tap)*64];
            const float* wrow = &w_s[tap*64*64 + f];
            #pragma unroll 16
            for (int d = 0; d < 64; ++d) acc += irow[d] * wrow[d*64];
        }
        float v = acc * scale + shift;
        x1h[((size_t)b*T + t0 + tt)*F + f] = __float2bfloat16(fmaxf(v, 0.0f));
    }
}

// ------------- MFMA bf16 GEMM: C[R,N] = A[R,K] @ Bt[N,K]^T + bias (+resid) -------------
// 128x128 tile per block, BK=32, 256 threads = 4 waves (2x2), 4x4 16x16 frags/wave.
// biasRow: bias indexed by row (for transposed-output formulations).
__global__ __launch_bounds__(256) void k_gemm(const bf16* __restrict__ A,
        const bf16* __restrict__ Bt, const float* __restrict__ bias,
        const bf16* __restrict__ resid, float* __restrict__ outF,
        bf16* __restrict__ outH, int K, int N, int biasRow)
{
    __shared__ short As[128*32];   // 8 KB
    __shared__ short Bs[128*32];   // 8 KB
    const int nbase = blockIdx.x * 128;
    const int rbase = blockIdx.y * 128;
    const int tid  = threadIdx.x;
    const int lane = tid & 63;
    const int wv   = tid >> 6;
    const int wm   = wv & 1;        // row half
    const int wn   = wv >> 1;       // col half
    const int l16  = lane & 15;
    const int quad = lane >> 4;

    floatx4 acc[4][4];
    #pragma unroll
    for (int i = 0; i < 4; ++i)
        #pragma unroll
        for (int j = 0; j < 4; ++j) acc[i][j] = (floatx4)0.0f;

    const int row  = tid >> 1;           // staging: 2 threads per tile-row
    const int koff = (tid & 1) * 16;     // 16 bf16 = 32 B per thread
    const int nK = K >> 5;
    for (int kt = 0; kt < nK; ++kt) {
        if (kt) __syncthreads();
        {
            const float4* ga = reinterpret_cast<const float4*>(
                &A[(size_t)(rbase + row)*K + kt*32 + koff]);
            const float4 a0 = ga[0], a1 = ga[1];
            const float4* gb = reinterpret_cast<const float4*>(
                &Bt[(size_t)(nbase + row)*K + kt*32 + koff]);
            const float4 b0 = gb[0], b1 = gb[1];
            float4* la = reinterpret_cast<float4*>(&As[row*32 + koff]);
            la[0] = a0; la[1] = a1;
            float4* lb = reinterpret_cast<float4*>(&Bs[row*32 + koff]);
            lb[0] = b0; lb[1] = b1;
        }
        __syncthreads();
        short8 af[4], bf[4];
        #pragma unroll
        for (int i = 0; i < 4; ++i)
            af[i] = *reinterpret_cast<const short8*>(&As[(wm*64 + i*16 + l16)*32 + quad*8]);
        #pragma unroll
        for (int j = 0; j < 4; ++j)
            bf[j] = *reinterpret_cast<const short8*>(&Bs[(wn*64 + j*16 + l16)*32 + quad*8]);
        #pragma unroll
        for (int i = 0; i < 4; ++i)
            #pragma unroll
            for (int j = 0; j < 4; ++j)
                acc[i][j] = __builtin_amdgcn_mfma_f32_16x16x32_bf16(af[i], bf[j], acc[i][j], 0, 0, 0);
    }

    #pragma unroll
    for (int j = 0; j < 4; ++j) {
        const int gcol = nbase + wn*64 + j*16 + l16;
        const float bj = biasRow ? 0.0f : bias[gcol];
        #pragma unroll
        for (int i = 0; i < 4; ++i) {
            #pragma unroll
            for (int r = 0; r < 4; ++r) {
                const int grow = rbase + wm*64 + i*16 + quad*4 + r;
                const size_t off = (size_t)grow*N + gcol;
                float v = acc[i][j][r] + (biasRow ? bias[grow] : bj);
                if (resid) v += __bfloat162float(resid[off]);
                if (outF) outF[off] = v;
                if (outH) outH[off] = __float2bfloat16(v);
            }
        }
    }
}

// ---------------- GRU scan: one block per (batch, direction) ----------------
__device__ __forceinline__ float sigmoidf_(float x){ return 1.0f/(1.0f + __expf(-x)); }
__device__ __forceinline__ float tanhf_(float x){ return 2.0f/(1.0f + __expf(-2.0f*x)) - 1.0f; }

__device__ __forceinline__ float xload(const float* p){ return *p; }
__device__ __forceinline__ float xload(const bf16* p){ return __bfloat162float(*p); }

template<typename XT>
__global__ __launch_bounds__(384, 1) void k_gru(const XT* __restrict__ xg_f,
        const XT* __restrict__ xg_b, const float* __restrict__ wh_f,
        const float* __restrict__ wh_b, const float* __restrict__ b_f,
        const float* __restrict__ b_b, bf16* __restrict__ yseq,
        float* __restrict__ hout)
{
    const int b   = blockIdx.x;
    const int dir = blockIdx.y;
    const XT* xg = dir ? xg_b : xg_f;               // [B,T,3U]
    const float* wh = dir ? wh_b : wh_f;            // [U,3U]
    const float* bh_ptr = (dir ? b_b : b_f) + G3;   // b[1]
    const int j = threadIdx.x;                      // gate column 0..383

    float2 w2[64];
    #pragma unroll
    for (int u = 0; u < 64; ++u) {
        w2[u].x = wh[(size_t)(2*u  )*G3 + j];
        w2[u].y = wh[(size_t)(2*u+1)*G3 + j];
    }
    const float bh = bh_ptr[j];

    __shared__ __align__(16) float h_s[U];
    __shared__ float hg_s[G3];
    if (j < U) h_s[j] = 0.0f;
    __syncthreads();

    for (int step = 0; step < T; ++step) {
        const int t = dir ? (T - 1 - step) : step;
        float xz = 0.f, xr = 0.f, xn = 0.f;
        if (j < U) {
            const XT* xrow = xg + ((size_t)b*T + t)*G3;
            xz = xload(xrow + j);
            xr = xload(xrow + U + j);
            xn = xload(xrow + 2*U + j);
        }
        const float4* h4 = reinterpret_cast<const float4*>(h_s);
        float a0 = 0.f, a1 = 0.f, a2 = 0.f, a3 = 0.f;
        #pragma unroll
        for (int u = 0; u < 32; ++u) {
            const float4 hv = h4[u];
            a0 = fmaf(hv.x, w2[2*u].x,   a0);
            a1 = fmaf(hv.y, w2[2*u].y,   a1);
            a2 = fmaf(hv.z, w2[2*u+1].x, a2);
            a3 = fmaf(hv.w, w2[2*u+1].y, a3);
        }
        hg_s[j] = ((a0 + a1) + (a2 + a3)) + bh;
        __syncthreads();
        if (j < U) {
            const float z = sigmoidf_(xz + hg_s[j]);
            const float r = sigmoidf_(xr + hg_s[U+j]);
            const float n = tanhf_(xn + r*hg_s[2*U+j]);
            const float hnew = z*h_s[j] + (1.0f - z)*n;
            h_s[j] = hnew;
            if (yseq) yseq[((size_t)b*T + t)*M2 + dir*U + j] = __float2bfloat16(hnew);
        }
        __syncthreads();
    }
    if (hout && j < U) hout[b*M2 + dir*U + j] = h_s[j];
}

// ---------------- MFMA flash attention ----------------
// Q,K,O: [B*T, HD] bf16 (head h at col h*KD). VT: [HD, B*T] bf16 (transposed V).
// Block = (qt, b, h): 64 q-rows. 4 waves, 16 q-rows each.
// S^T = K.Q^T  ->  C-layout: q = lane&15, key = quad*4+reg  (softmax state scalar/lane)
// P via LDS -> A-layout; O += P.V using VT B-frags.  O aliases Q (own rows only).
__global__ __launch_bounds__(256) void k_attn(const bf16* __restrict__ Q,
        const bf16* __restrict__ Kp, const bf16* __restrict__ VT,
        bf16* __restrict__ O)
{
    __shared__ short k_s[64*136];    // 17408 B: K tile  [key][d], pad 136
    __shared__ short vt_s[128*72];   // 18432 B: V^T tile [d][key], pad 72
    __shared__ short p_s[64*72];     //  9216 B: P tile  [q][key],  pad 72
    const int qt = blockIdx.x;       // 0..7
    const int b  = blockIdx.y;
    const int h  = blockIdx.z;
    const int tid  = threadIdx.x;
    const int lane = tid & 63;
    const int wv   = tid >> 6;
    const int l16  = lane & 15;
    const int quad = lane >> 4;

    // Q B-frags from global, once (q = qt*64 + wv*16 + l16)
    short8 qfrag[4];
    {
        const size_t qoff = (size_t)(b*T + qt*64 + wv*16 + l16)*HD + h*KD + quad*8;
        #pragma unroll
        for (int kt = 0; kt < 4; ++kt)
            qfrag[kt] = *reinterpret_cast<const short8*>(&Q[qoff + kt*32]);
    }

    floatx4 Oa[8];
    #pragma unroll
    for (int nf = 0; nf < 8; ++nf) Oa[nf] = (floatx4)0.0f;
    float mrun = -1e30f, lrun = 0.0f;

    for (int kg = 0; kg < 8; ++kg) {
        __syncthreads();             // prev iter's MFMA reads of k_s/vt_s done
        #pragma unroll
        for (int it = 0; it < 4; ++it) {      // K tile: 1024 chunks of 8 bf16
            const int linear = it*256 + tid;
            const int key = linear >> 4;
            const int dc  = linear & 15;
            const float4 v = *reinterpret_cast<const float4*>(
                &Kp[(size_t)(b*T + kg*64 + key)*HD + h*KD + dc*8]);
            *reinterpret_cast<float4*>(&k_s[key*136 + dc*8]) = v;
        }
        #pragma unroll
        for (int it = 0; it < 4; ++it) {      // V^T tile: 1024 chunks of 8 bf16
            const int linear = it*256 + tid;
            const int d  = linear >> 3;
            const int kc = linear & 7;
            const float4 v = *reinterpret_cast<const float4*>(
                &VT[(size_t)(h*KD + d)*BT + b*T + kg*64 + kc*8]);
            *reinterpret_cast<float4*>(&vt_s[d*72 + kc*8]) = v;
        }
        __syncthreads();
        // S^T = K.Q^T
        floatx4 s[4];
        #pragma unroll
        for (int kb = 0; kb < 4; ++kb) s[kb] = (floatx4)0.0f;
        #pragma unroll
        for (int kt = 0; kt < 4; ++kt) {
            #pragma unroll
            for (int kb = 0; kb < 4; ++kb) {
                const short8 af = *reinterpret_cast<const short8*>(
                    &k_s[(kb*16 + l16)*136 + kt*32 + quad*8]);
                s[kb] = __builtin_amdgcn_mfma_f32_16x16x32_bf16(af, qfrag[kt], s[kb], 0, 0, 0);
            }
        }
        // online softmax over keys (per q = l16; reduce in-lane then across quads)
        float kmax = -1e30f;
        #pragma unroll
        for (int kb = 0; kb < 4; ++kb)
            #pragma unroll
            for (int r = 0; r < 4; ++r) {
                s[kb][r] *= 0.08838834764831845f;   // 1/sqrt(128)
                kmax = fmaxf(kmax, s[kb][r]);
            }
        kmax = fmaxf(kmax, __shfl_xor(kmax, 16));
        kmax = fmaxf(kmax, __shfl_xor(kmax, 32));
        const float mnew  = fmaxf(mrun, kmax);
        const float alpha = __expf(mrun - mnew);
        float psum = 0.0f;
        #pragma unroll
        for (int kb = 0; kb < 4; ++kb)
            #pragma unroll
            for (int r = 0; r < 4; ++r) {
                const float p = __expf(s[kb][r] - mnew);
                s[kb][r] = p;
                psum += p;
            }
        psum += __shfl_xor(psum, 16);
        psum += __shfl_xor(psum, 32);
        lrun = lrun*alpha + psum;
        mrun = mnew;
        // rescale O accum (alpha for q=quad*4+r lives at lane quad*4+r)
        #pragma unroll
        for (int r = 0; r < 4; ++r) {
            const float ar = __shfl(alpha, quad*4 + r);
            #pragma unroll
            for (int nf = 0; nf < 8; ++nf) Oa[nf][r] *= ar;
        }
        // P -> LDS (A-layout rows; wave-local, no barrier needed: own rows only)
        bf16* pb = reinterpret_cast<bf16*>(p_s);
        #pragma unroll
        for (int kb = 0; kb < 4; ++kb)
            #pragma unroll
            for (int r = 0; r < 4; ++r)
                pb[(wv*16 + l16)*72 + kb*16 + quad*4 + r] = __float2bfloat16(s[kb][r]);
        // O += P.V
        #pragma unroll
        for (int kt2 = 0; kt2 < 2; ++kt2) {
            const short8 pf = *reinterpret_cast<const short8*>(
                &p_s[(wv*16 + l16)*72 + kt2*32 + quad*8]);
            #pragma unroll
            for (int nf = 0; nf < 8; ++nf) {
                const short8 vf = *reinterpret_cast<const short8*>(
                    &vt_s[(nf*16 + l16)*72 + kt2*32 + quad*8]);
                Oa[nf] = __builtin_amdgcn_mfma_f32_16x16x32_bf16(pf, vf, Oa[nf], 0, 0, 0);
            }
        }
    }
    // epilogue: O /= l, write (own q rows, own head cols -> in-place over Q safe)
    float linv[4];
    #pragma unroll
    for (int r = 0; r < 4; ++r) linv[r] = 1.0f / __shfl(lrun, quad*4 + r);
    #pragma unroll
    for (int nf = 0; nf < 8; ++nf)
        #pragma unroll
        for (int r = 0; r < 4; ++r) {
            const size_t row = (size_t)(b*T + qt*64 + wv*16 + quad*4 + r);
            O[row*HD + h*KD + nf*16 + l16] = __float2bfloat16(Oa[nf][r] * linv[r]);
        }
}

// ---------------- dense head ----------------
__global__ void k_dense(const float* __restrict__ h2, const float* __restrict__ dw,
                        const float* __restrict__ db, float* __restrict__ out)
{
    const int b = threadIdx.x;
    float acc = db[0];
    for (int mm = 0; mm < M2; ++mm) acc += h2[b*M2 + mm] * dw[mm];
    out[b] = acc;
}

extern "C" void kernel_launch(void* const* d_in, const int* in_sizes, int n_in,
                              void* d_out, int out_size, void* d_ws, size_t ws_size,
                              hipStream_t stream)
{
    const float* inputs  = (const float*)d_in[0];
    const float* conv_w  = (const float*)d_in[1];
    const float* conv_b  = (const float*)d_in[2];
    const float* bn_g    = (const float*)d_in[3];
    const float* bn_b    = (const float*)d_in[4];
    const float* bn_m    = (const float*)d_in[5];
    const float* bn_v    = (const float*)d_in[6];
    const float* g1f_wx  = (const float*)d_in[7];
    const float* g1f_wh  = (const float*)d_in[8];
    const float* g1f_b   = (const float*)d_in[9];
    const float* g1b_wx  = (const float*)d_in[10];
    const float* g1b_wh  = (const float*)d_in[11];
    const float* g1b_b   = (const float*)d_in[12];
    const float* wq      = (const float*)d_in[13];
    const float* bq      = (const float*)d_in[14];
    const float* wk      = (const float*)d_in[15];
    const float* bk      = (const float*)d_in[16];
    const float* wv_     = (const float*)d_in[17];
    const float* bv      = (const float*)d_in[18];
    const float* wo      = (const float*)d_in[19];
    const float* bo      = (const float*)d_in[20];
    const float* g2f_wx  = (const float*)d_in[21];
    const float* g2f_wh  = (const float*)d_in[22];
    const float* g2f_b   = (const float*)d_in[23];
    const float* g2b_wx  = (const float*)d_in[24];
    const float* g2b_wh  = (const float*)d_in[25];
    const float* g2b_b   = (const float*)d_in[26];
    const float* dense_w = (const float*)d_in[27];
    const float* dense_b = (const float*)d_in[28];
    float* out = (float*)d_out;
    (void)in_sizes; (void)n_in; (void)out_size; (void)ws_size;

    // ---- workspace (float-slot offsets into 128 MiB = 33,554,432 fslots) ----
    float* ws = (float*)d_ws;
    bf16* wb = (bf16*)ws;
    bf16* g1fT = wb;            // [384,64]
    bf16* g1bT = wb + 24576;
    bf16* wqT  = wb + 49152;    // [512,256]
    bf16* wkT  = wb + 180224;
    bf16* wvT  = wb + 311296;   // [512,256] -> used as GEMM-A for V^T
    bf16* woT  = wb + 442368;   // [256,512]
    bf16* g2fT = wb + 573440;   // [384,256]
    bf16* g2bT = wb + 671744;   // ends 770048 < 786432

    bf16*  x1h  = (bf16*)(ws + 393216);     // [B*T,64]
    float* xg1f = ws + 1441792;             // [B*T,384] fp32
    float* xg1b = ws + 14024704;            // [B*T,384] fp32
    bf16*  y1h  = (bf16*)(ws + 26607616);   // [B*T,256]
    bf16*  qh   = (bf16*)(ws + 393216);     // [B*T,512]
    bf16*  kh   = (bf16*)(ws + 8781824);    // [B*T,512]
    bf16*  vtg  = (bf16*)(ws + 17170432);   // [512, B*T]  (V transposed)
    bf16*  Oh   = qh;                       // attention output in-place
    bf16*  x2h  = (bf16*)(ws + 17170432);   // [B*T,256] (over dead vtg)
    bf16*  xg2f = (bf16*)(ws + 393216);     // [B*T,384]
    bf16*  xg2b = (bf16*)(ws + 6684672);
    float* h2   = ws + 12976128;            // [B,256]

    // 0. weight casts
    k_wcast<<<(64*384+255)/256, 256, 0, stream>>>(g1f_wx, g1fT, 64, 384);
    k_wcast<<<(64*384+255)/256, 256, 0, stream>>>(g1b_wx, g1bT, 64, 384);
    k_wcast<<<(256*512+255)/256, 256, 0, stream>>>(wq,  wqT, 256, 512);
    k_wcast<<<(256*512+255)/256, 256, 0, stream>>>(wk,  wkT, 256, 512);
    k_wcast<<<(256*512+255)/256, 256, 0, stream>>>(wv_, wvT, 256, 512);
    k_wcast<<<(512*256+255)/256, 256, 0, stream>>>(wo,  woT, 512, 256);
    k_wcast<<<(256*384+255)/256, 256, 0, stream>>>(g2f_wx, g2fT, 256, 384);
    k_wcast<<<(256*384+255)/256, 256, 0, stream>>>(g2b_wx, g2bT, 256, 384);

    // 1. conv + BN + ReLU -> x1h
    k_conv<<<dim3(T/16, B), 256, 0, stream>>>(inputs, conv_w, conv_b,
                                              bn_g, bn_b, bn_m, bn_v, x1h);
    // 2. GRU1 input gates (fp32)
    k_gemm<<<dim3(3, 256), 256, 0, stream>>>(x1h, g1fT, g1f_b, nullptr, xg1f, nullptr, 64, G3, 0);
    k_gemm<<<dim3(3, 256), 256, 0, stream>>>(x1h, g1bT, g1b_b, nullptr, xg1b, nullptr, 64, G3, 0);
    // 3. GRU1 scan -> y1h
    k_gru<float><<<dim3(B,2), 384, 0, stream>>>(xg1f, xg1b, g1f_wh, g1b_wh,
                                                g1f_b, g1b_b, y1h, nullptr);
    // 4. Q,K projections; V as transposed GEMM: vtg[d][t] = wvT[d,:].y1[t,:] + bv[d]
    k_gemm<<<dim3(4, 256), 256, 0, stream>>>(y1h, wqT, bq, nullptr, nullptr, qh, 256, HD, 0);
    k_gemm<<<dim3(4, 256), 256, 0, stream>>>(y1h, wkT, bk, nullptr, nullptr, kh, 256, HD, 0);
    k_gemm<<<dim3(BT/128, 4), 256, 0, stream>>>(wvT, y1h, bv, nullptr, nullptr, vtg, 256, BT, 1);
    // 5. MFMA flash attention, O in-place over Q
    k_attn<<<dim3(T/64, B, NH), 256, 0, stream>>>(qh, kh, vtg, Oh);
    // 6. output projection + bias + residual(y1h) -> x2h
    k_gemm<<<dim3(2, 256), 256, 0, stream>>>(Oh, woT, bo, y1h, nullptr, x2h, HD, M2, 0);
    // 7. GRU2 input gates (bf16)
    k_gemm<<<dim3(3, 256), 256, 0, stream>>>(x2h, g2fT, g2f_b, nullptr, nullptr, xg2f, 256, G3, 0);
    k_gemm<<<dim3(3, 256), 256, 0, stream>>>(x2h, g2bT, g2b_b, nullptr, nullptr, xg2b, 256, G3, 0);
    // 8. GRU2 scan -> h2
    k_gru<bf16><<<dim3(B,2), 384, 0, stream>>>(xg2f, xg2b, g2f_wh, g2b_wh,
                                               g2f_b, g2b_b, nullptr, h2);
    // 9. dense head
    k_dense<<<1, 64, 0, stream>>>(h2, dense_w, dense_b, out);
}